// Round 6
// baseline (252148.511 us; speedup 1.0000x reference)
//
#include <hip/hip_runtime.h>

#define SS 16384
#define DD 1024
#define HH 1024
#define G4H 4096
#define RING 512
#define SENT64 0xFFFFFFFFFFFFFFFFull

typedef unsigned long long u64;
typedef unsigned int u32;
typedef unsigned short ushort_t;

typedef __attribute__((ext_vector_type(8))) short bf16x8;
typedef __attribute__((ext_vector_type(4))) float f32x4;
typedef __attribute__((ext_vector_type(2))) _Float16 half2_t;

__device__ __forceinline__ float sigm(float x){ return 1.0f/(1.0f+__expf(-x)); }
__device__ __forceinline__ float tanh_fast(float x){ return 1.0f - 2.0f/(__expf(2.0f*x)+1.0f); }

__device__ __forceinline__ ushort_t f2bf(float f){
    u32 u = __float_as_uint(f);
    u32 r = (u + 0x7FFFu + ((u>>16)&1u)) >> 16;
    return (ushort_t)r;
}

#if __has_builtin(__builtin_amdgcn_fdot2)
__device__ __forceinline__ float FDOT2(half2_t a, half2_t b, float c){
    return __builtin_amdgcn_fdot2(a, b, c, false);
}
#else
__device__ __forceinline__ float FDOT2(half2_t a, half2_t b, float c){
    return c + (float)a.x*(float)b.x + (float)a.y*(float)b.y;
}
#endif

// ---------------- prep: fp32 -> bf16 conversions + bias ----------------
__global__ __launch_bounds__(256) void prep_kernel(
    const float* __restrict__ x, const float* __restrict__ wih,
    const float* __restrict__ bih, const float* __restrict__ bhh,
    ushort_t* __restrict__ xb, ushort_t* __restrict__ wb, float* __restrict__ bias)
{
    long long i = (long long)blockIdx.x*256 + threadIdx.x;
    const long long NX = (long long)SS*DD;      // 16777216
    const long long NW = (long long)G4H*DD;     // 4194304
    if (i < NX) { xb[i] = f2bf(x[i]); }
    else if (i < NX+NW) { long long j=i-NX; wb[j]=f2bf(wih[j]); }
    else { int j=(int)(i-NX-NW); if (j < G4H) bias[j]=bih[j]+bhh[j]; }
}

// ---------------- GEMM: xgT[t][unit][gate] = x @ W_ih^T + bias (fp16) ----------------
#define LDA 40  // padded LDS row stride (bf16 elems)

__global__ __launch_bounds__(256) void gemm_kernel(
    const ushort_t* __restrict__ A, const ushort_t* __restrict__ B,
    const float* __restrict__ bias, _Float16* __restrict__ Cg)
{
    __shared__ ushort_t At[128*LDA];
    __shared__ ushort_t Bt[128*LDA];
    const int tid  = threadIdx.x;
    const int lane = tid & 63;
    const int wv   = tid >> 6;
    const int wm   = wv >> 1, wn = wv & 1;
    const int m0   = blockIdx.y * 128;
    const int n0   = blockIdx.x * 128;
    const int quad = lane >> 4;
    const int l16  = lane & 15;

    f32x4 acc[4][4];
    #pragma unroll
    for (int a=0;a<4;a++)
      #pragma unroll
      for (int b=0;b<4;b++) acc[a][b] = (f32x4){0.f,0.f,0.f,0.f};

    for (int kb = 0; kb < DD; kb += 32) {
        #pragma unroll
        for (int s=0;s<2;s++){
            int ch  = tid*2+s;            // 0..511
            int row = ch >> 2;
            int ko  = (ch & 3) * 8;
            uint4 va = *(const uint4*)(A + (long long)(m0+row)*DD + kb + ko);
            *(uint4*)(At + row*LDA + ko) = va;
            uint4 vb = *(const uint4*)(B + (long long)(n0+row)*DD + kb + ko);
            *(uint4*)(Bt + row*LDA + ko) = vb;
        }
        __syncthreads();
        bf16x8 af[4], bfr[4];
        #pragma unroll
        for (int mi=0;mi<4;mi++){
            int r = wm*64 + mi*16 + l16;
            af[mi] = *(const bf16x8*)(At + r*LDA + quad*8);
        }
        #pragma unroll
        for (int ni=0;ni<4;ni++){
            int r = wn*64 + ni*16 + l16;
            bfr[ni] = *(const bf16x8*)(Bt + r*LDA + quad*8);
        }
        #pragma unroll
        for (int mi=0;mi<4;mi++)
          #pragma unroll
          for (int ni=0;ni<4;ni++)
            acc[mi][ni] = __builtin_amdgcn_mfma_f32_16x16x32_bf16(af[mi], bfr[ni], acc[mi][ni], 0,0,0);
        __syncthreads();
    }
    #pragma unroll
    for (int mi=0;mi<4;mi++){
      #pragma unroll
      for (int ni=0;ni<4;ni++){
        int col = n0 + wn*64 + ni*16 + l16;
        float bv = bias[col];
        int unit = col & 1023, gate = col >> 10;
        #pragma unroll
        for (int r=0;r<4;r++){
            int rowg = m0 + wm*64 + mi*16 + quad*4 + r;
            Cg[(long long)rowg*G4H + unit*4 + gate] = (_Float16)(acc[mi][ni][r] + bv);
        }
      }
    }
}

// ---------------- persistent LSTM scan ----------------
// 1024 single-wave WGs, 8x replicated across XCDs. Fast path: per-XCD L2 ring
// (sc0 tag+payload, monotonic tags -> stale lines can never false-match).
// Fallback: self-signaling full-history hist (agent scope, sentinel 0xFF..F,
// unique address per step -> no ABA, no ordering needed). Data is consumed
// ONLY when verified -> all replicas bit-identical by induction.
__global__ __launch_bounds__(64, 1) void scan_kernel(
    const float* __restrict__ whh, const _Float16* __restrict__ xgT,
    u64* __restrict__ hist, char* __restrict__ ringP, char* __restrict__ ringT,
    u32* __restrict__ cnt)
{
    const int lane = threadIdx.x;        // 0..63
    const int l16  = lane & 15;          // column block (64 cols)
    const int grp  = lane >> 4;          // gate (i,f,g,o)

    u32 xcc;
    asm volatile("s_getreg_b32 %0, hwreg(HW_REG_XCC_ID)" : "=s"(xcc));
    xcc &= 7;

    u32 rank = 0;
    if (lane == 0)
        rank = __hip_atomic_fetch_add(&cnt[xcc], 1u, __ATOMIC_RELAXED, __HIP_MEMORY_SCOPE_AGENT);
    rank = __builtin_amdgcn_readfirstlane(rank);
    const int chunk = (int)(rank & 127u);   // 8 units: u0..u0+7
    const int u0    = chunk * 8;

    // fp16 weights in registers: Wreg[d][k] = W_hh[grp*H + u0+d][64*l16 + 2k .. +1]
    half2_t Wreg[8][32];
    #pragma unroll
    for (int d=0; d<8; ++d){
        const float* rp = whh + ((size_t)(grp*HH + u0 + d))*HH + 64*l16;
        #pragma unroll
        for (int k=0;k<32;k++){
            float2 f = *(const float2*)(rp + 2*k);
            half2_t hh; hh.x=(_Float16)f.x; hh.y=(_Float16)f.y;
            Wreg[d][k]=hh;
        }
    }

    char* tagX = ringT + (size_t)xcc*(RING*512);    // 256 KB per XCD
    char* payX = ringP + (size_t)xcc*(RING*2048);   // 1 MB per XCD

    float c_my = 0.f;                    // lane d<8: cell of unit u0+d
    u64 xcur = 0, xnx = 0;
    if (lane < 8) xcur = *(const u64*)((const char*)xgT + (size_t)(u0+lane)*8);

    int  fb_cnt  = 0;
    bool allslow = false;
    int  gspin   = 1<<18;                // fallback-poll insurance cap

    for (int t=0; t<SS; ++t){
        const int slot = t & (RING-1);
        half2_t h2[32];
        const bool have_h = (t > 0);
        if (have_h){
            const int pslot = (t-1) & (RING-1);
            const u64 expt = (u64)(u32)t | ((u64)(u32)t << 32);
            bool got = false;
            if (!allslow){
                char* ta = tagX + (size_t)pslot*512 + 8*lane;
                int b = (t == 1) ? (1<<14) : (1<<10);
                for(;;){
                    u64 tv;
                    asm volatile("global_load_dwordx2 %0, %1, off sc0\n\ts_waitcnt vmcnt(0)"
                                 : "=&v"(tv) : "v"(ta) : "memory");
                    if (__all(tv == expt)){ got = true; break; }
                    if (--b < 0) break;
                }
            }
            if (got){
                char* pa = payX + (size_t)pslot*2048 + 128*l16;
                uint4 p0,p1,p2,p3,p4,p5,p6,p7;
                asm volatile(
                    "global_load_dwordx4 %0, %4, off sc0\n\t"
                    "global_load_dwordx4 %1, %4, off offset:16 sc0\n\t"
                    "global_load_dwordx4 %2, %4, off offset:32 sc0\n\t"
                    "global_load_dwordx4 %3, %4, off offset:48 sc0"
                    : "=&v"(p0),"=&v"(p1),"=&v"(p2),"=&v"(p3) : "v"(pa) : "memory");
                asm volatile(
                    "global_load_dwordx4 %0, %4, off offset:64 sc0\n\t"
                    "global_load_dwordx4 %1, %4, off offset:80 sc0\n\t"
                    "global_load_dwordx4 %2, %4, off offset:96 sc0\n\t"
                    "global_load_dwordx4 %3, %4, off offset:112 sc0\n\t"
                    "s_waitcnt vmcnt(0)"
                    : "=&v"(p4),"=&v"(p5),"=&v"(p6),"=&v"(p7) : "v"(pa) : "memory");
                u32 wbuf[32] = {p0.x,p0.y,p0.z,p0.w, p1.x,p1.y,p1.z,p1.w,
                                p2.x,p2.y,p2.z,p2.w, p3.x,p3.y,p3.z,p3.w,
                                p4.x,p4.y,p4.z,p4.w, p5.x,p5.y,p5.z,p5.w,
                                p6.x,p6.y,p6.z,p6.w, p7.x,p7.y,p7.z,p7.w};
                #pragma unroll
                for (int k=0;k<32;k++){
                    union { u32 u; half2_t h; } cv; cv.u = wbuf[k]; h2[k] = cv.h;
                }
            } else {
                // correct fallback: self-signaling full-history (agent scope)
                fb_cnt++; if (fb_cnt >= 16) allslow = true;
                const u64* hrow = hist + (size_t)(t-1)*256 + 16*l16;
                u64 wv[16];
                for(;;){
                    bool ok = true;
                    #pragma unroll
                    for (int k=0;k<16;k++){
                        wv[k] = __hip_atomic_load(hrow+k, __ATOMIC_RELAXED, __HIP_MEMORY_SCOPE_AGENT);
                        ok = ok && (wv[k] != SENT64);
                    }
                    if (__all(ok)) break;
                    if (--gspin < 0) break;
                }
                #pragma unroll
                for (int k=0;k<16;k++){
                    union { u64 u; half2_t h[2]; } cv; cv.u = wv[k];
                    h2[2*k]   = cv.h[0];
                    h2[2*k+1] = cv.h[1];
                }
            }
        }
        // prefetch next step's xg (consumed after the next poll -> latency hidden)
        if (lane < 8 && t+1 < SS)
            xnx = *(const u64*)((const char*)xgT + (size_t)(t+1)*8192 + (size_t)(u0+lane)*8);

        float zi=0.f, zf=0.f, zg=0.f, zo=0.f;
        #pragma unroll
        for (int d=0; d<8; ++d){
            float a = 0.f;
            if (have_h){
                #pragma unroll
                for (int k=0;k<32;k++) a = FDOT2(Wreg[d][k], h2[k], a);
            }
            a += __shfl_xor(a,1,64); a += __shfl_xor(a,2,64);
            a += __shfl_xor(a,4,64); a += __shfl_xor(a,8,64);
            float gi = __shfl(a, 0, 64);
            float gf = __shfl(a, 16, 64);
            float gg = __shfl(a, 32, 64);
            float go = __shfl(a, 48, 64);
            if (lane == d){ zi=gi; zf=gf; zg=gg; zo=go; }
        }
        float hmy = 0.f;
        if (lane < 8){
            union { u64 u; _Float16 f[4]; } xv; xv.u = xcur;
            zi += (float)xv.f[0]; zf += (float)xv.f[1];
            zg += (float)xv.f[2]; zo += (float)xv.f[3];
            c_my = sigm(zf)*c_my + sigm(zi)*tanh_fast(zg);
            hmy  = sigm(zo)*tanh_fast(c_my);
        }
        // lanes 0/1 each pack 4 units
        const int p = lane & 1;
        float g0 = __shfl(hmy, 4*p+0, 64);
        float g1 = __shfl(hmy, 4*p+1, 64);
        float g2 = __shfl(hmy, 4*p+2, 64);
        float g3 = __shfl(hmy, 4*p+3, 64);
        u64 pk;
        { union { u64 u; _Float16 f[4]; } c;
          c.f[0]=(_Float16)g0; c.f[1]=(_Float16)g1;
          c.f[2]=(_Float16)g2; c.f[3]=(_Float16)g3; pk=c.u; }
        if (lane < 2){
            char* sp = payX + (size_t)slot*2048 + (size_t)chunk*16 + (size_t)p*8;
            asm volatile("global_store_dwordx2 %0, %1, off sc0" :: "v"(sp), "v"(pk) : "memory");
        }
        asm volatile("s_waitcnt vmcnt(0)" ::: "memory");   // payload in L2 before tag
        if (lane == 0){
            u32 tv = (u32)(t+1);
            char* tp = tagX + (size_t)slot*512 + (size_t)chunk*4;
            asm volatile("global_store_dword %0, %1, off sc0" :: "v"(tp), "v"(tv) : "memory");
        }
        // global publish: fire-and-forget (data is its own signal; unique address)
        if (lane < 2)
            __hip_atomic_store(&hist[(size_t)t*256 + chunk*2 + p], pk,
                               __ATOMIC_RELAXED, __HIP_MEMORY_SCOPE_AGENT);
        xcur = xnx;
    }
}

// ---------------- alpha = sigmoid(hs @ W_fc^T + b_fc) ----------------
__global__ __launch_bounds__(256) void alpha_kernel(
    const u64* __restrict__ packed, const float* __restrict__ wfc,
    const float* __restrict__ bfc, float* __restrict__ alpha)
{
    int row  = blockIdx.x*4 + (threadIdx.x>>6);
    int lane = threadIdx.x & 63;
    const u64* p = packed + (long long)row*256 + 4*lane;
    float s = 0.f;
    #pragma unroll
    for (int q=0;q<4;q++){
        union { u64 u; _Float16 h[4]; } cv; cv.u = p[q];
        float4 wvv = *(const float4*)(wfc + 16*lane + 4*q);
        s += (float)cv.h[0]*wvv.x + (float)cv.h[1]*wvv.y
           + (float)cv.h[2]*wvv.z + (float)cv.h[3]*wvv.w;
    }
    #pragma unroll
    for (int off=32; off>=1; off>>=1) s += __shfl_xor(s, off, 64);
    if (lane==0) alpha[row] = sigm(s + bfc[0]);
}

// ---------------- finalize: affine scans + loss ----------------
__global__ __launch_bounds__(256) void finalize_kernel(
    const float* __restrict__ uttr_pred, const float* __restrict__ timing_label,
    const float* __restrict__ alpha, float* __restrict__ out)
{
    const int n = SS-1;  // 16383
    const int tid = threadIdx.x;
    __shared__ float Ms[256], Cs[256], Pre[256];
    __shared__ int Fi[256];
    float* out_y = out + 1;
    float* out_a = out + 1 + n;
    float* out_u = out + 1 + 2*n;

    int i0 = tid*64;
    int i1 = i0+64; if (i1 > n) i1 = n;

    float M = 1.f, C = 0.f;
    int fi = 0x7fffffff;
    for (int i=i0; i<i1; ++i){
        float u = 1.f - uttr_pred[i+1];
        float a = alpha[i+1];
        out_u[i] = u;
        M = u*M;
        C = u*C + (1.f-u)*a;
        if (timing_label[i] > 0.8f && i < fi) fi = i;
    }
    Ms[tid]=M; Cs[tid]=C; Fi[tid]=fi;
    __syncthreads();
    if (tid==0){
        float x=0.f;
        for (int tt=0; tt<256; ++tt){ Pre[tt]=x; x = Ms[tt]*x + Cs[tt]; }
        int best=0x7fffffff;
        for (int tt=0; tt<256; ++tt) best = min(best, Fi[tt]);
        Fi[0]=best;
    }
    __syncthreads();
    float x = Pre[tid];
    float My=1.f, Cy=0.f;
    for (int i=i0;i<i1;++i){
        float u = 1.f - uttr_pred[i+1];
        float a = alpha[i+1];
        x = u*x + (1.f-u)*a;
        out_a[i] = x;
        float Af = 1.f - x;
        float Bf = x*u;
        My = Af*My;
        Cy = Af*Cy + Bf;
    }
    Ms[tid]=My; Cs[tid]=Cy;
    __syncthreads();
    if (tid==0){
        float y=0.f;
        for (int tt=0;tt<256;++tt){ Pre[tt]=y; y = Ms[tt]*y + Cs[tt]; }
    }
    __syncthreads();
    float y = Pre[tid];
    for (int i=i0;i<i1;++i){
        float ag = out_a[i];
        float u  = out_u[i];
        y = ag*u + (1.f-ag)*y;
        out_y[i] = y;
    }
    __syncthreads();
    if (tid==0){
        int best = Fi[0];
        bool exists = (best != 0x7fffffff);
        int idx = exists ? best : 0;
        float u_at = 1.f - uttr_pred[idx+1];
        float y_at = out_y[idx];
        float y_last = out_y[n-1];
        float loss;
        if (exists) loss = (u_at < 0.5f) ? 0.f : (y_at-0.8f)*(y_at-0.8f);
        else        loss = (y_last >= 0.8f) ? (y_last-0.4f)*(y_last-0.4f) : 0.f;
        out[0] = loss;
    }
}

// ---------------- launch ----------------
extern "C" void kernel_launch(void* const* d_in, const int* in_sizes, int n_in,
                              void* d_out, int out_size, void* d_ws, size_t ws_size,
                              hipStream_t stream)
{
    const float* x    = (const float*)d_in[0];
    const float* up   = (const float*)d_in[1];
    const float* tl   = (const float*)d_in[2];
    const float* wih  = (const float*)d_in[4];
    const float* whh  = (const float*)d_in[5];
    const float* bih  = (const float*)d_in[6];
    const float* bhh  = (const float*)d_in[7];
    const float* wfc  = (const float*)d_in[8];
    const float* bfc  = (const float*)d_in[9];
    float* out = (float*)d_out;

    char* ws = (char*)d_ws;
    // Phase A: xb @0 (32MB), wb @32M (8MB), xgT @40M (128MB), bias @176.16M (16KB)
    // Phase B (xb/bias dead): ringP @0 (8MB), ringT @8M (2MB), cnt @10,485,760,
    //          alp @11,534,336 (64KB), hist @176,160,768 (32MB)
    ushort_t* xb   = (ushort_t*)(ws);
    char*     ringP= ws;
    char*     ringT= ws + 8388608;
    u32*      cnt  = (u32*)(ws + 10485760);
    float*    alp  = (float*)(ws + 11534336);
    ushort_t* wb   = (ushort_t*)(ws + 33554432);
    _Float16* xgT  = (_Float16*)(ws + 41943040);
    u64*      hist = (u64*)(ws + 176160768);
    float*    bias = (float*)(ws + 176160768);

    prep_kernel<<<81936, 256, 0, stream>>>(x, wih, bih, bhh, xb, wb, bias);
    gemm_kernel<<<dim3(G4H/128, SS/128), 256, 0, stream>>>(xb, wb, bias, xgT);
    hipMemsetAsync(ringT, 0, 2097152, stream);     // ring tags = 0 (monotonic, never match t>=1)
    hipMemsetAsync(hist, 0xFF, 33554432, stream);  // hist sentinel
    hipMemsetAsync(cnt, 0, 64, stream);
    scan_kernel<<<1024, 64, 0, stream>>>(whh, xgT, hist, ringP, ringT, cnt);
    alpha_kernel<<<SS/4, 256, 0, stream>>>(hist, wfc, bfc, alp);
    finalize_kernel<<<1, 256, 0, stream>>>(up, tl, alp, out);
}